// Round 2
// baseline (3191.080 us; speedup 1.0000x reference)
//
#include <hip/hip_runtime.h>

// MAC forward, round 2.
// - All activations stored T-layout [C][32] so GEMMs read X as wave-uniform
//   scalar loads (SMEM) and accumulate acc[32] per lane (axpy style).
// - All weights pre-transposed once per call into Wt[C][N] row-major.
// - ra_w folded into ri_ws = diag(ra_w) @ ri_w upfront.
// - Small GEMMs: c-split across waves (in-block LDS tree reduce) and across
//   jobs (partial outputs summed by the consumer) -> no atomics.
// - ca_b / ra_b / ri_b softmax-invariant, dropped. cq_b/rm_b folded into
//   consumers (ctrl_att / ratt).

#define NSTEP 12

struct GJob {
  const float* X1;   // [c1][32] (T-layout)
  const float* X2;   // [C-c1][32] or null
  const float* Wt;   // [C][N] row-major
  const float* bias; // [N] or null
  float* out;        // [N][32] T-layout (or [32][N] if rm)
  long xg, wg, bg, og;  // per-group strides
  int c1, N, cbeg, clen, rm;
};

struct GArgs4 { GJob j[4]; };

// block = 512 thr = 8 waves; wave w covers c in [cbeg+w*CW, cbeg+(w+1)*CW),
// lane owns column n = bx*64+lane with acc[32] over b. X reads are
// wave-uniform -> scalar loads; W read is one coalesced dword per c.
__global__ __launch_bounds__(512) void gemm_xt(GArgs4 A) {
  __shared__ float red[7 * 64 * 32];  // 56 KB
  const GJob j = A.j[blockIdx.z];
  const int lane = threadIdx.x & 63;
  const int wave = threadIdx.x >> 6;
  const int g = blockIdx.y;
  const int n = blockIdx.x * 64 + lane;
  const int CW = j.clen >> 3;
  const int cb = j.cbeg + wave * CW;
  const float* __restrict__ xt =
      (cb < j.c1) ? j.X1 + (long)g * j.xg + (long)cb * 32
                  : j.X2 + (long)(cb - j.c1) * 32;
  const float* __restrict__ wt = j.Wt + (long)g * j.wg + (long)cb * j.N + n;
  float acc[32];
#pragma unroll
  for (int b = 0; b < 32; b++) acc[b] = 0.f;
  for (int c = 0; c < CW; ++c) {
    float w = wt[(long)c * j.N];
    const float* __restrict__ xr = xt + c * 32;
#pragma unroll
    for (int b = 0; b < 32; b++) acc[b] = fmaf(xr[b], w, acc[b]);
  }
  if (wave) {
    float* r = red + (wave - 1) * 64 * 32 + lane * 32;
#pragma unroll
    for (int b = 0; b < 32; b += 4)
      *(float4*)(r + b) = make_float4(acc[b], acc[b + 1], acc[b + 2], acc[b + 3]);
  }
  __syncthreads();
  if (wave == 0) {
#pragma unroll
    for (int w = 0; w < 7; w++) {
      const float* r = red + w * 64 * 32 + lane * 32;
#pragma unroll
      for (int b = 0; b < 32; b += 4) {
        float4 v = *(const float4*)(r + b);
        acc[b] += v.x; acc[b + 1] += v.y; acc[b + 2] += v.z; acc[b + 3] += v.w;
      }
    }
    float bv = j.bias ? j.bias[(long)g * j.bg + n] : 0.f;
    if (j.rm) {
      float* o = j.out + (long)g * j.og + n;
#pragma unroll
      for (int b = 0; b < 32; b++) o[(long)b * j.N] = acc[b] + bv;
    } else {
      float* o = j.out + (long)g * j.og + (long)n * 32;
#pragma unroll
      for (int b = 0; b < 32; b += 4)
        *(float4*)(o + b) = make_float4(acc[b] + bv, acc[b + 1] + bv,
                                        acc[b + 2] + bv, acc[b + 3] + bv);
    }
  }
}

// in [R][C] row-major -> out [C][R], per-group strides.
__global__ __launch_bounds__(1024) void transpose_k(const float* in, float* out,
                                                    int R, int C, long ing, long outg) {
  __shared__ float t[32][33];
  const float* I = in + (long)blockIdx.z * ing;
  float* O = out + (long)blockIdx.z * outg;
  int c0 = blockIdx.x * 32, r0 = blockIdx.y * 32;
  t[threadIdx.y][threadIdx.x] = I[(long)(r0 + threadIdx.y) * C + c0 + threadIdx.x];
  __syncthreads();
  O[(long)(c0 + threadIdx.y) * R + r0 + threadIdx.x] = t[threadIdx.x][threadIdx.y];
}

__global__ __launch_bounds__(1024) void init_control_kernel(const float* ci, float* control_t) {
  control_t[blockIdx.x * 1024 + threadIdx.x] = ci[0];
}

// ri_ws[c][n] = ri_w[c][n] * ra_w[c]   (fold xscale into the weight)
__global__ __launch_bounds__(1024) void riws_kernel(const float* ri_w, const float* ra_w,
                                                    float* riws) {
  int i = blockIdx.x * 1024 + threadIdx.x;
  riws[i] = ri_w[i] * ra_w[i >> 11];
}

// control-unit attention. cq = cq_p0 + cq_p1 + qc_s + cq_b (partials summed
// here). One block (1024 thr) per batch row; writes control_t (T-layout).
__global__ __launch_bounds__(1024) void ctrl_att_kernel(const float* cq_p, const float* qc_s,
                                                        const float* cq_b, const float* context,
                                                        const float* ca_w, float* control_t) {
  int b = blockIdx.x;
  __shared__ float u[1024];
  __shared__ float sc[128];
  int tid = threadIdx.x;
  int wave = tid >> 6, lane = tid & 63;
  float cqv = cq_p[tid * 32 + b] + cq_p[32 * 1024 + tid * 32 + b] +
              qc_s[tid * 32 + b] + cq_b[tid];
  u[tid] = cqv * ca_w[tid];
  __syncthreads();
  const float* ctx = context + (long)b * 128 * 1024;
#pragma unroll
  for (int i = 0; i < 8; i++) {
    int s = wave * 8 + i;
    float v = 0.f;
#pragma unroll
    for (int c = 0; c < 16; c++) v += u[c * 64 + lane] * ctx[(long)s * 1024 + c * 64 + lane];
#pragma unroll
    for (int off = 32; off; off >>= 1) v += __shfl_xor(v, off, 64);
    if (lane == 0) sc[s] = v;
  }
  __syncthreads();
  if (wave == 0) {
    float a0 = sc[lane], a1 = sc[lane + 64];
    float m = fmaxf(a0, a1);
#pragma unroll
    for (int off = 32; off; off >>= 1) m = fmaxf(m, __shfl_xor(m, off, 64));
    float e0 = expf(a0 - m), e1 = expf(a1 - m);
    float s2 = e0 + e1;
#pragma unroll
    for (int off = 32; off; off >>= 1) s2 += __shfl_xor(s2, off, 64);
    float inv = 1.f / s2;
    sc[lane] = e0 * inv;
    sc[lane + 64] = e1 * inv;
  }
  __syncthreads();
  float acc = 0.f;
  for (int s = 0; s < 128; s++) acc += sc[s] * ctx[(long)s * 1024 + tid];
  control_t[tid * 32 + b] = acc;
}

// r_att partials over j-chunks. memp/h arrive as 2 c-chunk partials each;
// rm_b folded here. partial[jc][b][k] = sum_{j in chunk} g[b,j]*knowledge[b,j,k]
__global__ __launch_bounds__(512) void ratt_kernel(const float* knowledge, const float* memp_p,
                                                   const float* h_p, const float* rm_b,
                                                   float* partial) {
  int b = blockIdx.x, jc = blockIdx.y;
  int j0 = jc * 64;
  __shared__ float gl[64];
  if (threadIdx.x < 64) {
    int j = j0 + threadIdx.x;
    float mp = memp_p[j * 32 + b] + memp_p[32 * 1024 + j * 32 + b] + rm_b[j];
    float h1 = h_p[j * 32 + b] + h_p[2048 * 32 + j * 32 + b];
    float h2 = h_p[(1024 + j) * 32 + b] + h_p[2048 * 32 + (1024 + j) * 32 + b];
    gl[threadIdx.x] = mp * h1 + h2;
  }
  __syncthreads();
  int k = threadIdx.x;
  const float* kb = knowledge + ((long)b * 1024 + j0) * 512 + k;
  float acc = 0.f;
#pragma unroll 8
  for (int jj = 0; jj < 64; jj++) acc += gl[jj] * kb[(long)jj * 512];
  partial[((long)jc * 32 + b) * 512 + k] = acc;
}

// softmax(r_att) + read_t[d][b] = sum_k a[k]*knowledge[b,d,k]
__global__ __launch_bounds__(256) void read_kernel(const float* partial, const float* knowledge,
                                                   float* read_t) {
  int b = blockIdx.x, dg = blockIdx.y;
  __shared__ float aw[512];
  __shared__ float red[4];
  int tid = threadIdx.x;
  int wave = tid >> 6, lane = tid & 63;
  int k0 = tid * 2;
  float r0 = 0.f, r1 = 0.f;
#pragma unroll
  for (int p = 0; p < 16; p++) {
    const float* pp = partial + ((long)p * 32 + b) * 512;
    r0 += pp[k0];
    r1 += pp[k0 + 1];
  }
  float m = fmaxf(r0, r1);
#pragma unroll
  for (int off = 32; off; off >>= 1) m = fmaxf(m, __shfl_xor(m, off, 64));
  if (lane == 0) red[wave] = m;
  __syncthreads();
  m = fmaxf(fmaxf(red[0], red[1]), fmaxf(red[2], red[3]));
  __syncthreads();
  float e0 = expf(r0 - m), e1 = expf(r1 - m);
  float s2 = e0 + e1;
#pragma unroll
  for (int off = 32; off; off >>= 1) s2 += __shfl_xor(s2, off, 64);
  if (lane == 0) red[wave] = s2;
  __syncthreads();
  s2 = red[0] + red[1] + red[2] + red[3];
  float inv = 1.f / s2;
  aw[k0] = e0 * inv;
  aw[k0 + 1] = e1 * inv;
  __syncthreads();
  int d0 = dg * 32 + wave * 8;
  float acc[8];
#pragma unroll
  for (int i = 0; i < 8; i++) acc[i] = 0.f;
  const float* kb = knowledge + ((long)b * 1024 + d0) * 512;
  for (int kc = 0; kc < 8; kc++) {
    int kk = kc * 64 + lane;
    float av = aw[kk];
#pragma unroll
    for (int dd = 0; dd < 8; dd++) acc[dd] += av * kb[(long)dd * 512 + kk];
  }
#pragma unroll
  for (int dd = 0; dd < 8; dd++) {
    float v = acc[dd];
#pragma unroll
    for (int off = 32; off; off >>= 1) v += __shfl_xor(v, off, 64);
    if (lane == dd) read_t[(d0 + dd) * 32 + b] = v;
  }
}

static inline GJob mkjob(const float* X1, const float* X2, int c1, const float* Wt,
                         const float* bias, float* out, long xg, long wg, long bg, long og,
                         int N, int cbeg, int clen, int rm) {
  GJob j; j.X1 = X1; j.X2 = X2; j.Wt = Wt; j.bias = bias; j.out = out;
  j.xg = xg; j.wg = wg; j.bg = bg; j.og = og;
  j.c1 = c1; j.N = N; j.cbeg = cbeg; j.clen = clen; j.rm = rm;
  return j;
}

extern "C" void kernel_launch(void* const* d_in, const int* in_sizes, int n_in,
                              void* d_out, int out_size, void* d_ws, size_t ws_size,
                              hipStream_t stream) {
  const float* context      = (const float*)d_in[0];
  const float* question     = (const float*)d_in[1];
  const float* knowledge    = (const float*)d_in[2];
  const float* control_init = (const float*)d_in[3];
  const float* pa_w = (const float*)d_in[4];
  const float* pa_b = (const float*)d_in[5];
  const float* cq_w = (const float*)d_in[6];
  const float* cq_b = (const float*)d_in[7];
  const float* ca_w = (const float*)d_in[8];
  const float* rm_w = (const float*)d_in[10];
  const float* rm_b = (const float*)d_in[11];
  const float* ri_w = (const float*)d_in[12];
  const float* ra_w = (const float*)d_in[14];
  const float* wm_w = (const float*)d_in[16];
  const float* wm_b = (const float*)d_in[17];
  float* out = (float*)d_out;

  float* p = (float*)d_ws;
  float* cqT       = p; p += 2048 * 1024;
  float* rmT       = p; p += 1024 * 1024;
  float* wmT       = p; p += 2048 * 1024;
  float* riws      = p; p += 1024 * 2048;
  float* questionT = p; p += 2048 * 32;
  float* q_pa_t    = p; p += NSTEP * 1024 * 32;
  float* qc_t      = p; p += NSTEP * 1024 * 32;
  float* control_t = p; p += 1024 * 32;
  float* memA      = p; p += 1024 * 32;
  float* memB      = p; p += 1024 * 32;
  float* cq_p      = p; p += 2 * 1024 * 32;
  float* memp_p    = p; p += 2 * 1024 * 32;
  float* h_p       = p; p += 2 * 2048 * 32;
  float* partial   = p; p += 16 * 32 * 512;
  float* read_t    = p; p += 1024 * 32;
  float* paT       = p;  // up to 12 * 2048*1024 floats, chunked if ws is short

  long used = (long)(p - (float*)d_ws);
  long avail = (long)(ws_size / 4) - used;
  int GC = (int)(avail / (2048L * 1024));
  if (GC > NSTEP) GC = NSTEP;
  if (GC < 1) GC = 1;  // assume ws >= ~43 MB

  // ---- upfront ----
  transpose_k<<<dim3(64, 32, 1), dim3(32, 32), 0, stream>>>(cq_w, cqT, 1024, 2048, 0, 0);
  transpose_k<<<dim3(32, 32, 1), dim3(32, 32), 0, stream>>>(rm_w, rmT, 1024, 1024, 0, 0);
  transpose_k<<<dim3(64, 32, 1), dim3(32, 32), 0, stream>>>(wm_w, wmT, 1024, 2048, 0, 0);
  transpose_k<<<dim3(64, 1, 1), dim3(32, 32), 0, stream>>>(question, questionT, 32, 2048, 0, 0);
  riws_kernel<<<2048, 1024, 0, stream>>>(ri_w, ra_w, riws);
  init_control_kernel<<<32, 1024, 0, stream>>>(control_init, control_t);

  // q_pa_all[s] = question @ pa_w[s].T + pa_b[s]   (pa transposed in chunks)
  for (int s0 = 0; s0 < NSTEP; s0 += GC) {
    int gc = NSTEP - s0 < GC ? NSTEP - s0 : GC;
    transpose_k<<<dim3(64, 32, gc), dim3(32, 32), 0, stream>>>(
        pa_w + (long)s0 * 1024 * 2048, paT, 1024, 2048, 2048L * 1024, 2048L * 1024);
    GArgs4 A;
    A.j[0] = mkjob(questionT, nullptr, 1 << 30, paT, pa_b + (long)s0 * 1024,
                   q_pa_t + (long)s0 * 1024 * 32, 0, 2048L * 1024, 1024, 1024 * 32,
                   1024, 0, 2048, 0);
    A.j[1] = A.j[0]; A.j[2] = A.j[0]; A.j[3] = A.j[0];
    gemm_xt<<<dim3(16, gc, 1), 512, 0, stream>>>(A);
  }
  // qc_all[s] = q_pa_all[s] @ cq_w[:, D:].T
  {
    GArgs4 A;
    A.j[0] = mkjob(q_pa_t, nullptr, 1 << 30, cqT + 1024 * 1024, nullptr, qc_t,
                   1024 * 32, 0, 0, 1024 * 32, 1024, 0, 1024, 0);
    A.j[1] = A.j[0]; A.j[2] = A.j[0]; A.j[3] = A.j[0];
    gemm_xt<<<dim3(16, NSTEP, 1), 512, 0, stream>>>(A);
  }

  for (int s = 0; s < NSTEP; s++) {
    const float* mo = (s == 0) ? q_pa_t : ((s & 1) ? memA : memB);
    float* mn = (s == NSTEP - 1) ? out : ((s & 1) ? memB : memA);
    // G1 (cq partials) + G2 (mem_p partials), one 4-job launch
    {
      GArgs4 A;
      A.j[0] = mkjob(control_t, nullptr, 1 << 30, cqT, nullptr, cq_p,
                     0, 0, 0, 0, 1024, 0, 512, 0);
      A.j[1] = mkjob(control_t, nullptr, 1 << 30, cqT, nullptr, cq_p + 1024 * 32,
                     0, 0, 0, 0, 1024, 512, 512, 0);
      A.j[2] = mkjob(mo, nullptr, 1 << 30, rmT, nullptr, memp_p,
                     0, 0, 0, 0, 1024, 0, 512, 0);
      A.j[3] = mkjob(mo, nullptr, 1 << 30, rmT, nullptr, memp_p + 1024 * 32,
                     0, 0, 0, 0, 1024, 512, 512, 0);
      gemm_xt<<<dim3(16, 1, 4), 512, 0, stream>>>(A);
    }
    ctrl_att_kernel<<<32, 1024, 0, stream>>>(cq_p, qc_t + (long)s * 1024 * 32, cq_b,
                                             context, ca_w, control_t);
    // G3: h = control @ ri_ws (2 c-chunk partial jobs)
    {
      GArgs4 A;
      A.j[0] = mkjob(control_t, nullptr, 1 << 30, riws, nullptr, h_p,
                     0, 0, 0, 0, 2048, 0, 512, 0);
      A.j[1] = mkjob(control_t, nullptr, 1 << 30, riws, nullptr, h_p + 2048 * 32,
                     0, 0, 0, 0, 2048, 512, 512, 0);
      A.j[2] = A.j[0]; A.j[3] = A.j[0];
      gemm_xt<<<dim3(32, 1, 2), 512, 0, stream>>>(A);
    }
    ratt_kernel<<<dim3(32, 16), 512, 0, stream>>>(knowledge, memp_p, h_p, rm_b, partial);
    read_kernel<<<dim3(32, 32), 256, 0, stream>>>(partial, knowledge, read_t);
    // G6: new_memory = [read, memory] @ wm_w.T + wm_b  (full sum, one job)
    {
      GArgs4 A;
      A.j[0] = mkjob(read_t, mo, 1024, wmT, wm_b, mn,
                     0, 0, 0, 0, 1024, 0, 2048, (s == NSTEP - 1) ? 1 : 0);
      A.j[1] = A.j[0]; A.j[2] = A.j[0]; A.j[3] = A.j[0];
      gemm_xt<<<dim3(16, 1, 1), 512, 0, stream>>>(A);
    }
  }
}

// Round 3
// 1871.037 us; speedup vs baseline: 1.7055x; 1.7055x over previous
//
#include <hip/hip_runtime.h>

// MAC forward, round 3. Back to round-1 structure (row-major activations,
// LDS-staged X tile, wave-owns-n gemm) with the LDS-throughput fix:
// each wave computes U output columns per ds_read_b128 (acc[U][32]),
// cutting LDS bytes/FLOP by U. U=4 for the batched upfront gemms,
// U=2 for per-step gemms (more blocks -> better spread).
// Only one weight transpose (ri_w, fused with ra_w scale). No partials.

#define NSTEP 12

struct GJob {
  const float* X1;   // [32][c1] row-major
  const float* X2;   // [32][C-c1] or unused (set c1 = C)
  const float* W;    // [N][ldw] row-major, rows contiguous over c
  const float* bias; // [N] or null
  const float* add;  // [32][N] or null
  float* out;        // [32][N]
  long xg, wg, bg, og;  // per-group (blockIdx.y) strides
  int c1, C, ldw, N;
};
struct GJobs { GJob j[2]; };

// block = 256 thr = 4 waves; wave owns U consecutive n (n0..n0+U-1); lane
// covers c = chunk + lane*4. X chunk (32 x 256) staged in LDS (32 KB).
// Inner: 32 ds_read_b128 feed U*32*4 FMAs. Butterfly-reduce over lanes.
template <int U>
__global__ __launch_bounds__(256) void gemm_k(GJobs A) {
  __shared__ float xs[32 * 256];
  const GJob j = A.j[blockIdx.z];
  const int lane = threadIdx.x & 63;
  const int wave = threadIdx.x >> 6;
  const int g = blockIdx.y;
  const int n0 = blockIdx.x * (4 * U) + wave * U;
  const float* __restrict__ X1 = j.X1 + (long)g * j.xg;
  const float* __restrict__ Wp = j.W + (long)g * j.wg;
  const int C = j.C, c1 = j.c1;
  const int cs2 = C - c1;
  float acc[U][32];
#pragma unroll
  for (int u = 0; u < U; u++)
#pragma unroll
    for (int b = 0; b < 32; b++) acc[u][b] = 0.f;

  for (int c0 = 0; c0 < C; c0 += 256) {
    __syncthreads();
#pragma unroll
    for (int i = 0; i < 8; i++) {
      int idx = threadIdx.x + i * 256;  // 2048 float4 slots = 32 x 64
      int b = idx >> 6, c4 = idx & 63;
      int c = c0 + c4 * 4;
      float4 v;
      if (c < c1) v = *(const float4*)(X1 + (long)b * c1 + c);
      else        v = *(const float4*)(j.X2 + (long)b * cs2 + (c - c1));
      *(float4*)(xs + b * 256 + c4 * 4) = v;
    }
    __syncthreads();
    const int cl = lane * 4;
    float4 wv[U];
#pragma unroll
    for (int u = 0; u < U; u++)
      wv[u] = *(const float4*)(Wp + (long)(n0 + u) * j.ldw + c0 + cl);
#pragma unroll
    for (int b = 0; b < 32; b++) {
      float4 xv = *(const float4*)(xs + b * 256 + cl);
#pragma unroll
      for (int u = 0; u < U; u++)
        acc[u][b] += xv.x * wv[u].x + xv.y * wv[u].y + xv.z * wv[u].z + xv.w * wv[u].w;
    }
  }
#pragma unroll
  for (int u = 0; u < U; u++) {
    float res = 0.f;
#pragma unroll
    for (int b = 0; b < 32; b++) {
      float v = acc[u][b];
#pragma unroll
      for (int off = 32; off; off >>= 1) v += __shfl_xor(v, off, 64);
      if (lane == b) res = v;
    }
    if (lane < 32) {
      const int n = n0 + u;
      float o = res;
      if (j.bias) o += j.bias[(long)g * j.bg + n];
      if (j.add) o += j.add[(long)lane * j.N + n];
      j.out[(long)g * j.og + (long)lane * j.N + n] = o;
    }
  }
}

__global__ __launch_bounds__(1024) void init_control_kernel(const float* ci, float* control) {
  control[blockIdx.x * 1024 + threadIdx.x] = ci[0];
}

// riwsT[j][d] = ri_w[d][j] * ra_w[d]   (transpose + fold attention weight)
__global__ void riwsT_kernel(const float* ri_w, const float* ra_w, float* o) {
  __shared__ float t[32][33];
  int j0 = blockIdx.x * 32, d0 = blockIdx.y * 32;
  t[threadIdx.y][threadIdx.x] =
      ri_w[(long)(d0 + threadIdx.y) * 2048 + j0 + threadIdx.x] * ra_w[d0 + threadIdx.y];
  __syncthreads();
  o[(long)(j0 + threadIdx.y) * 1024 + d0 + threadIdx.x] = t[threadIdx.x][threadIdx.y];
}

// control-unit attention: scores over context, softmax, new_control.
// One block (1024 thr) per batch row. ca_b dropped (softmax-invariant).
__global__ __launch_bounds__(1024) void ctrl_att_kernel(const float* cq, const float* context,
                                                        const float* ca_w, float* control) {
  int b = blockIdx.x;
  __shared__ float u[1024];
  __shared__ float sc[128];
  int tid = threadIdx.x;
  int wave = tid >> 6, lane = tid & 63;
  u[tid] = cq[b * 1024 + tid] * ca_w[tid];
  __syncthreads();
  const float* ctx = context + (long)b * 128 * 1024;
#pragma unroll
  for (int i = 0; i < 8; i++) {
    int s = wave * 8 + i;  // 16 waves x 8 = 128 scores
    float v = 0.f;
#pragma unroll
    for (int c = 0; c < 16; c++) v += u[c * 64 + lane] * ctx[(long)s * 1024 + c * 64 + lane];
#pragma unroll
    for (int off = 32; off; off >>= 1) v += __shfl_xor(v, off, 64);
    if (lane == 0) sc[s] = v;
  }
  __syncthreads();
  if (wave == 0) {
    float a0 = sc[lane], a1 = sc[lane + 64];
    float m = fmaxf(a0, a1);
#pragma unroll
    for (int off = 32; off; off >>= 1) m = fmaxf(m, __shfl_xor(m, off, 64));
    float e0 = expf(a0 - m), e1 = expf(a1 - m);
    float s2 = e0 + e1;
#pragma unroll
    for (int off = 32; off; off >>= 1) s2 += __shfl_xor(s2, off, 64);
    float inv = 1.f / s2;
    sc[lane] = e0 * inv;
    sc[lane + 64] = e1 * inv;
  }
  __syncthreads();
  float acc = 0.f;
  for (int s = 0; s < 128; s++) acc += sc[s] * ctx[(long)s * 1024 + tid];
  control[b * 1024 + tid] = acc;
}

// r_att partials: partial[jc][b][k] = sum_{j in chunk jc} g[b,j]*knowledge[b,j,k]
// g = mem_p * h[:, :1024] + h[:, 1024:]  (rm_b already folded into mem_p bias)
__global__ __launch_bounds__(512) void ratt_kernel(const float* knowledge, const float* mem_p,
                                                   const float* h, float* partial) {
  int b = blockIdx.x, jc = blockIdx.y;
  int j0 = jc * 64;
  __shared__ float gl[64];
  if (threadIdx.x < 64) {
    int j = j0 + threadIdx.x;
    gl[threadIdx.x] = mem_p[b * 1024 + j] * h[b * 2048 + j] + h[b * 2048 + 1024 + j];
  }
  __syncthreads();
  int k = threadIdx.x;
  const float* kb = knowledge + ((long)b * 1024 + j0) * 512 + k;
  float acc = 0.f;
#pragma unroll 8
  for (int jj = 0; jj < 64; jj++) acc += gl[jj] * kb[(long)jj * 512];
  partial[((long)jc * 32 + b) * 512 + k] = acc;
}

// softmax(r_att) + read[b,d] = sum_k a[k]*knowledge[b,d,k]
__global__ __launch_bounds__(256) void read_kernel(const float* partial, const float* knowledge,
                                                   float* readv) {
  int b = blockIdx.x, dg = blockIdx.y;
  __shared__ float aw[512];
  __shared__ float red[4];
  int tid = threadIdx.x;
  int wave = tid >> 6, lane = tid & 63;
  int k0 = tid * 2;
  float r0 = 0.f, r1 = 0.f;
#pragma unroll
  for (int p = 0; p < 16; p++) {
    const float* pp = partial + ((long)p * 32 + b) * 512;
    r0 += pp[k0];
    r1 += pp[k0 + 1];
  }
  float m = fmaxf(r0, r1);
#pragma unroll
  for (int off = 32; off; off >>= 1) m = fmaxf(m, __shfl_xor(m, off, 64));
  if (lane == 0) red[wave] = m;
  __syncthreads();
  m = fmaxf(fmaxf(red[0], red[1]), fmaxf(red[2], red[3]));
  __syncthreads();
  float e0 = expf(r0 - m), e1 = expf(r1 - m);
  float s2 = e0 + e1;
#pragma unroll
  for (int off = 32; off; off >>= 1) s2 += __shfl_xor(s2, off, 64);
  if (lane == 0) red[wave] = s2;
  __syncthreads();
  s2 = red[0] + red[1] + red[2] + red[3];
  float inv = 1.f / s2;
  aw[k0] = e0 * inv;
  aw[k0 + 1] = e1 * inv;
  __syncthreads();
  int d0 = dg * 32 + wave * 8;
  float acc[8];
#pragma unroll
  for (int i = 0; i < 8; i++) acc[i] = 0.f;
  const float* kb = knowledge + ((long)b * 1024 + d0) * 512;
  for (int kc = 0; kc < 8; kc++) {
    int kk = kc * 64 + lane;
    float av = aw[kk];
#pragma unroll
    for (int dd = 0; dd < 8; dd++) acc[dd] += av * kb[(long)dd * 512 + kk];
  }
#pragma unroll
  for (int dd = 0; dd < 8; dd++) {
    float v = acc[dd];
#pragma unroll
    for (int off = 32; off; off >>= 1) v += __shfl_xor(v, off, 64);
    if (lane == dd) readv[b * 1024 + d0 + dd] = v;
  }
}

static inline GJob mkjob(const float* X1, const float* X2, int c1, int C,
                         const float* W, int ldw, const float* bias, const float* add,
                         float* out, int N, long xg, long wg, long bg, long og) {
  GJob j; j.X1 = X1; j.X2 = X2; j.W = W; j.bias = bias; j.add = add; j.out = out;
  j.xg = xg; j.wg = wg; j.bg = bg; j.og = og;
  j.c1 = c1; j.C = C; j.ldw = ldw; j.N = N;
  return j;
}

extern "C" void kernel_launch(void* const* d_in, const int* in_sizes, int n_in,
                              void* d_out, int out_size, void* d_ws, size_t ws_size,
                              hipStream_t stream) {
  const float* context      = (const float*)d_in[0];
  const float* question     = (const float*)d_in[1];
  const float* knowledge    = (const float*)d_in[2];
  const float* control_init = (const float*)d_in[3];
  const float* pa_w = (const float*)d_in[4];
  const float* pa_b = (const float*)d_in[5];
  const float* cq_w = (const float*)d_in[6];
  const float* cq_b = (const float*)d_in[7];
  const float* ca_w = (const float*)d_in[8];
  const float* rm_w = (const float*)d_in[10];
  const float* rm_b = (const float*)d_in[11];
  const float* ri_w = (const float*)d_in[12];
  const float* ra_w = (const float*)d_in[14];
  const float* wm_w = (const float*)d_in[16];
  const float* wm_b = (const float*)d_in[17];
  float* out = (float*)d_out;

  float* p = (float*)d_ws;
  float* riwsT   = p; p += 2048 * 1024;        // [2048 j][1024 d]
  float* q_pa    = p; p += NSTEP * 32 * 1024;  // [s][32][1024]
  float* qc      = p; p += NSTEP * 32 * 1024;  // [s][32][1024]
  float* control = p; p += 32 * 1024;
  float* memA    = p; p += 32 * 1024;
  float* memB    = p; p += 32 * 1024;
  float* cq      = p; p += 32 * 1024;
  float* mem_p   = p; p += 32 * 1024;
  float* h       = p; p += 32 * 2048;
  float* partial = p; p += 16 * 32 * 512;
  float* readv   = p; p += 32 * 1024;

  // ---- upfront ----
  riwsT_kernel<<<dim3(64, 32), dim3(32, 32), 0, stream>>>(ri_w, ra_w, riwsT);
  init_control_kernel<<<32, 1024, 0, stream>>>(control_init, control);
  {  // q_pa[s] = question @ pa_w[s].T + pa_b[s]   (U=4, 64x12 blocks)
    GJobs A;
    A.j[0] = mkjob(question, nullptr, 2048, 2048, pa_w, 2048, pa_b, nullptr,
                   q_pa, 1024, 0, 1024L * 2048, 1024, 32 * 1024);
    A.j[1] = A.j[0];
    gemm_k<4><<<dim3(64, NSTEP, 1), 256, 0, stream>>>(A);
  }
  {  // qc[s] = q_pa[s] @ cq_w[:, 1024:].T
    GJobs A;
    A.j[0] = mkjob(q_pa, nullptr, 1024, 1024, cq_w + 1024, 2048, nullptr, nullptr,
                   qc, 1024, 32 * 1024, 0, 0, 32 * 1024);
    A.j[1] = A.j[0];
    gemm_k<4><<<dim3(64, NSTEP, 1), 256, 0, stream>>>(A);
  }

  for (int s = 0; s < NSTEP; s++) {
    const float* mo = (s == 0) ? q_pa : ((s & 1) ? memA : memB);
    float* mn = (s == NSTEP - 1) ? out : ((s & 1) ? memB : memA);
    {  // G1: cq = control @ cq_w[:, :1024].T + qc[s] + cq_b
       // G2: mem_p = memory @ rm_w.T + rm_b      (fused, z = 2 jobs)
      GJobs A;
      A.j[0] = mkjob(control, nullptr, 1024, 1024, cq_w, 2048, cq_b,
                     qc + (long)s * 32 * 1024, cq, 1024, 0, 0, 0, 0);
      A.j[1] = mkjob(mo, nullptr, 1024, 1024, rm_w, 1024, rm_b, nullptr,
                     mem_p, 1024, 0, 0, 0, 0);
      gemm_k<2><<<dim3(128, 1, 2), 256, 0, stream>>>(A);
    }
    ctrl_att_kernel<<<32, 1024, 0, stream>>>(cq, context, ca_w, control);
    {  // G3: h = control @ riwsT.T   (N=2048, C=1024)
      GJobs A;
      A.j[0] = mkjob(control, nullptr, 1024, 1024, riwsT, 1024, nullptr, nullptr,
                     h, 2048, 0, 0, 0, 0);
      A.j[1] = A.j[0];
      gemm_k<2><<<dim3(256, 1, 1), 256, 0, stream>>>(A);
    }
    ratt_kernel<<<dim3(32, 16), 512, 0, stream>>>(knowledge, mem_p, h, partial);
    read_kernel<<<dim3(32, 32), 256, 0, stream>>>(partial, knowledge, readv);
    {  // G6: new_memory = [read, memory] @ wm_w.T + wm_b
      GJobs A;
      A.j[0] = mkjob(readv, mo, 1024, 2048, wm_w, 2048, wm_b, nullptr,
                     mn, 1024, 0, 0, 0, 0);
      A.j[1] = A.j[0];
      gemm_k<2><<<dim3(128, 1, 1), 256, 0, stream>>>(A);
    }
  }
}

// Round 4
// 1780.553 us; speedup vs baseline: 1.7922x; 1.0508x over previous
//
#include <hip/hip_runtime.h>

// MAC forward, round 4. Round-3 structure + memory-depth fixes:
//  - gemm_v4: register-prefetch of next X chunk + W burst issued before the
//    barrier -> ~12 float4/lane in flight (round 3 had 2-4 => 330 GB/s cap).
//  - LDS-transpose epilogue replaces 768-shfl butterfly.
//  - ctrl_att phase 2: 4 independent accumulators, full unroll (was a
//    dependent 128-load latency chain).
// Algebra unchanged: inter2 GEMM collapsed via linearity; qc hoisted;
// softmax-invariant biases dropped.

#define NSTEP 12

struct GJob {
  const float* X1;   // [32][c1] row-major
  const float* X2;   // [32][C-c1] or unused (set c1 = C)
  const float* W;    // [N][ldw] row-major
  const float* bias; // [N] or null
  const float* add;  // [32][N] or null
  float* out;        // [32][N]
  long xg, wg, bg, og;  // per-group (blockIdx.y) strides
  int c1, C, ldw, N;
};
struct GJobs { GJob j[2]; };

// Block 256 thr = 4 waves; wave owns 4 output cols (n0..n0+3); block owns 16.
// K chunked at 256 floats; X chunk (32x256) staged via register prefetch.
__global__ __launch_bounds__(256, 2) void gemm_v4(GJobs A) {
  __shared__ float smem[8704];  // 34 KB: X tile (8192 f) / epilogue 4*32*68
  const GJob j = A.j[blockIdx.z];
  const int lane = threadIdx.x & 63;
  const int wave = threadIdx.x >> 6;
  const int g = blockIdx.y;
  const int n0 = blockIdx.x * 16 + wave * 4;
  const float* __restrict__ X1 = j.X1 + (long)g * j.xg;
  const float* __restrict__ X2 = j.X2;
  const float* __restrict__ Wp = j.W + (long)g * j.wg;
  const int C = j.C, c1 = j.c1, cs2 = C - c1;

  float acc[4][32];
#pragma unroll
  for (int u = 0; u < 4; u++)
#pragma unroll
    for (int b = 0; b < 32; b++) acc[u][b] = 0.f;

  float4 xpre[8];
  auto loadx = [&](int c0) {
#pragma unroll
    for (int i = 0; i < 8; i++) {
      int slot = threadIdx.x + i * 256;  // 2048 fl4 slots = 32 rows x 64
      int b = slot >> 6, c4 = slot & 63;
      int c = c0 + c4 * 4;
      xpre[i] = (c < c1) ? *(const float4*)(X1 + (long)b * c1 + c)
                         : *(const float4*)(X2 + (long)b * cs2 + (c - c1));
    }
  };
  loadx(0);

  for (int c0 = 0; c0 < C; c0 += 256) {
    __syncthreads();  // previous FMA reads done; smem free
#pragma unroll
    for (int i = 0; i < 8; i++) {
      int slot = threadIdx.x + i * 256;
      int b = slot >> 6, c4 = slot & 63;
      *(float4*)(smem + b * 256 + c4 * 4) = xpre[i];
    }
    // W burst for this chunk + X prefetch for next: in flight over barrier
    float4 wv[4];
    const int cl = c0 + lane * 4;
#pragma unroll
    for (int u = 0; u < 4; u++)
      wv[u] = *(const float4*)(Wp + (long)(n0 + u) * j.ldw + cl);
    if (c0 + 256 < C) loadx(c0 + 256);
    __syncthreads();
#pragma unroll
    for (int b = 0; b < 32; b++) {
      float4 xv = *(const float4*)(smem + b * 256 + lane * 4);
#pragma unroll
      for (int u = 0; u < 4; u++)
        acc[u][b] += xv.x * wv[u].x + xv.y * wv[u].y + xv.z * wv[u].z + xv.w * wv[u].w;
    }
  }

  // Epilogue: per-wave LDS transpose reduce (wave-private region, stride 68
  // keeps float4 alignment and spreads banks).
  __syncthreads();
  float* sr = smem + wave * (32 * 68);
  float outv[4];
#pragma unroll
  for (int u = 0; u < 4; u++) {
#pragma unroll
    for (int b = 0; b < 32; b++) sr[b * 68 + lane] = acc[u][b];
    float s = 0.f;
    if (lane < 32) {
      const float4* r = (const float4*)(sr + lane * 68);
#pragma unroll
      for (int i = 0; i < 16; i++) { float4 v = r[i]; s += (v.x + v.y) + (v.z + v.w); }
    }
    outv[u] = s;
  }
  if (lane < 32) {
#pragma unroll
    for (int u = 0; u < 4; u++) {
      int n = n0 + u;
      float o = outv[u];
      if (j.bias) o += j.bias[(long)g * j.bg + n];
      if (j.add) o += j.add[(long)lane * j.N + n];
      j.out[(long)g * j.og + (long)lane * j.N + n] = o;
    }
  }
}

__global__ __launch_bounds__(1024) void init_control_kernel(const float* ci, float* control) {
  control[blockIdx.x * 1024 + threadIdx.x] = ci[0];
}

// riwsT[j][d] = ri_w[d][j] * ra_w[d]   (transpose + fold attention weight)
__global__ void riwsT_kernel(const float* ri_w, const float* ra_w, float* o) {
  __shared__ float t[32][33];
  int j0 = blockIdx.x * 32, d0 = blockIdx.y * 32;
  t[threadIdx.y][threadIdx.x] =
      ri_w[(long)(d0 + threadIdx.y) * 2048 + j0 + threadIdx.x] * ra_w[d0 + threadIdx.y];
  __syncthreads();
  o[(long)(j0 + threadIdx.y) * 1024 + d0 + threadIdx.x] = t[threadIdx.x][threadIdx.y];
}

// control-unit attention: scores over context, softmax, new_control.
__global__ __launch_bounds__(1024) void ctrl_att_kernel(const float* cq, const float* context,
                                                        const float* ca_w, float* control) {
  int b = blockIdx.x;
  __shared__ float u[1024];
  __shared__ float sc[128];
  int tid = threadIdx.x;
  int wave = tid >> 6, lane = tid & 63;
  u[tid] = cq[b * 1024 + tid] * ca_w[tid];
  __syncthreads();
  const float* ctx = context + (long)b * 128 * 1024;
#pragma unroll
  for (int i = 0; i < 8; i++) {
    int s = wave * 8 + i;  // 16 waves x 8 = 128 scores
    float v = 0.f;
#pragma unroll
    for (int c = 0; c < 16; c++) v += u[c * 64 + lane] * ctx[(long)s * 1024 + c * 64 + lane];
#pragma unroll
    for (int off = 32; off; off >>= 1) v += __shfl_xor(v, off, 64);
    if (lane == 0) sc[s] = v;
  }
  __syncthreads();
  if (wave == 0) {
    float a0 = sc[lane], a1 = sc[lane + 64];
    float m = fmaxf(a0, a1);
#pragma unroll
    for (int off = 32; off; off >>= 1) m = fmaxf(m, __shfl_xor(m, off, 64));
    float e0 = expf(a0 - m), e1 = expf(a1 - m);
    float s2 = e0 + e1;
#pragma unroll
    for (int off = 32; off; off >>= 1) s2 += __shfl_xor(s2, off, 64);
    float inv = 1.f / s2;
    sc[lane] = e0 * inv;
    sc[lane + 64] = e1 * inv;
  }
  __syncthreads();
  float a0 = 0.f, a1 = 0.f, a2 = 0.f, a3 = 0.f;
#pragma unroll
  for (int s = 0; s < 128; s += 4) {
    a0 += sc[s] * ctx[(long)s * 1024 + tid];
    a1 += sc[s + 1] * ctx[(long)(s + 1) * 1024 + tid];
    a2 += sc[s + 2] * ctx[(long)(s + 2) * 1024 + tid];
    a3 += sc[s + 3] * ctx[(long)(s + 3) * 1024 + tid];
  }
  control[b * 1024 + tid] = (a0 + a1) + (a2 + a3);
}

// r_att partials: partial[jc][b][k] = sum_{j in chunk jc} g[b,j]*knowledge[b,j,k]
__global__ __launch_bounds__(512) void ratt_kernel(const float* knowledge, const float* mem_p,
                                                   const float* h, float* partial) {
  int b = blockIdx.x, jc = blockIdx.y;
  int j0 = jc * 64;
  __shared__ float gl[64];
  if (threadIdx.x < 64) {
    int j = j0 + threadIdx.x;
    gl[threadIdx.x] = mem_p[b * 1024 + j] * h[b * 2048 + j] + h[b * 2048 + 1024 + j];
  }
  __syncthreads();
  int k = threadIdx.x;
  const float* kb = knowledge + ((long)b * 1024 + j0) * 512 + k;
  float acc = 0.f;
#pragma unroll 8
  for (int jj = 0; jj < 64; jj++) acc += gl[jj] * kb[(long)jj * 512];
  partial[((long)jc * 32 + b) * 512 + k] = acc;
}

// softmax(r_att) + read[b,d] = sum_k a[k]*knowledge[b,d,k]
__global__ __launch_bounds__(256) void read_kernel(const float* partial, const float* knowledge,
                                                   float* readv) {
  int b = blockIdx.x, dg = blockIdx.y;
  __shared__ float aw[512];
  __shared__ float red[4];
  int tid = threadIdx.x;
  int wave = tid >> 6, lane = tid & 63;
  int k0 = tid * 2;
  float r0 = 0.f, r1 = 0.f;
#pragma unroll
  for (int p = 0; p < 16; p++) {
    const float* pp = partial + ((long)p * 32 + b) * 512;
    r0 += pp[k0];
    r1 += pp[k0 + 1];
  }
  float m = fmaxf(r0, r1);
#pragma unroll
  for (int off = 32; off; off >>= 1) m = fmaxf(m, __shfl_xor(m, off, 64));
  if (lane == 0) red[wave] = m;
  __syncthreads();
  m = fmaxf(fmaxf(red[0], red[1]), fmaxf(red[2], red[3]));
  __syncthreads();
  float e0 = expf(r0 - m), e1 = expf(r1 - m);
  float s2 = e0 + e1;
#pragma unroll
  for (int off = 32; off; off >>= 1) s2 += __shfl_xor(s2, off, 64);
  if (lane == 0) red[wave] = s2;
  __syncthreads();
  s2 = red[0] + red[1] + red[2] + red[3];
  float inv = 1.f / s2;
  aw[k0] = e0 * inv;
  aw[k0 + 1] = e1 * inv;
  __syncthreads();
  int d0 = dg * 32 + wave * 8;
  float acc[8];
#pragma unroll
  for (int i = 0; i < 8; i++) acc[i] = 0.f;
  const float* kb = knowledge + ((long)b * 1024 + d0) * 512;
  for (int kc = 0; kc < 8; kc++) {
    int kk = kc * 64 + lane;
    float av = aw[kk];
#pragma unroll
    for (int dd = 0; dd < 8; dd++) acc[dd] += av * kb[(long)dd * 512 + kk];
  }
#pragma unroll
  for (int dd = 0; dd < 8; dd++) {
    float v = acc[dd];
#pragma unroll
    for (int off = 32; off; off >>= 1) v += __shfl_xor(v, off, 64);
    if (lane == dd) readv[b * 1024 + d0 + dd] = v;
  }
}

static inline GJob mkjob(const float* X1, const float* X2, int c1, int C,
                         const float* W, int ldw, const float* bias, const float* add,
                         float* out, int N, long xg, long wg, long bg, long og) {
  GJob j; j.X1 = X1; j.X2 = X2; j.W = W; j.bias = bias; j.add = add; j.out = out;
  j.xg = xg; j.wg = wg; j.bg = bg; j.og = og;
  j.c1 = c1; j.C = C; j.ldw = ldw; j.N = N;
  return j;
}

extern "C" void kernel_launch(void* const* d_in, const int* in_sizes, int n_in,
                              void* d_out, int out_size, void* d_ws, size_t ws_size,
                              hipStream_t stream) {
  const float* context      = (const float*)d_in[0];
  const float* question     = (const float*)d_in[1];
  const float* knowledge    = (const float*)d_in[2];
  const float* control_init = (const float*)d_in[3];
  const float* pa_w = (const float*)d_in[4];
  const float* pa_b = (const float*)d_in[5];
  const float* cq_w = (const float*)d_in[6];
  const float* cq_b = (const float*)d_in[7];
  const float* ca_w = (const float*)d_in[8];
  const float* rm_w = (const float*)d_in[10];
  const float* rm_b = (const float*)d_in[11];
  const float* ri_w = (const float*)d_in[12];
  const float* ra_w = (const float*)d_in[14];
  const float* wm_w = (const float*)d_in[16];
  const float* wm_b = (const float*)d_in[17];
  float* out = (float*)d_out;

  float* p = (float*)d_ws;
  float* riwsT   = p; p += 2048 * 1024;        // [2048 j][1024 d]
  float* q_pa    = p; p += NSTEP * 32 * 1024;  // [s][32][1024]
  float* qc      = p; p += NSTEP * 32 * 1024;  // [s][32][1024]
  float* control = p; p += 32 * 1024;
  float* memA    = p; p += 32 * 1024;
  float* memB    = p; p += 32 * 1024;
  float* cq      = p; p += 32 * 1024;
  float* mem_p   = p; p += 32 * 1024;
  float* h       = p; p += 32 * 2048;
  float* partial = p; p += 16 * 32 * 512;
  float* readv   = p; p += 32 * 1024;

  // ---- upfront ----
  riwsT_kernel<<<dim3(64, 32), dim3(32, 32), 0, stream>>>(ri_w, ra_w, riwsT);
  init_control_kernel<<<32, 1024, 0, stream>>>(control_init, control);
  {  // q_pa[s] = question @ pa_w[s].T + pa_b[s]
    GJobs A;
    A.j[0] = mkjob(question, nullptr, 2048, 2048, pa_w, 2048, pa_b, nullptr,
                   q_pa, 1024, 0, 1024L * 2048, 1024, 32 * 1024);
    A.j[1] = A.j[0];
    gemm_v4<<<dim3(64, NSTEP, 1), 256, 0, stream>>>(A);
  }
  {  // qc[s] = q_pa[s] @ cq_w[:, 1024:].T
    GJobs A;
    A.j[0] = mkjob(q_pa, nullptr, 1024, 1024, cq_w + 1024, 2048, nullptr, nullptr,
                   qc, 1024, 32 * 1024, 0, 0, 32 * 1024);
    A.j[1] = A.j[0];
    gemm_v4<<<dim3(64, NSTEP, 1), 256, 0, stream>>>(A);
  }

  for (int s = 0; s < NSTEP; s++) {
    const float* mo = (s == 0) ? q_pa : ((s & 1) ? memA : memB);
    float* mn = (s == NSTEP - 1) ? out : ((s & 1) ? memB : memA);
    {  // G1: cq = control @ cq_w[:, :1024].T + qc[s] + cq_b
       // G2: mem_p = memory @ rm_w.T + rm_b      (fused, z = 2 jobs)
      GJobs A;
      A.j[0] = mkjob(control, nullptr, 1024, 1024, cq_w, 2048, cq_b,
                     qc + (long)s * 32 * 1024, cq, 1024, 0, 0, 0, 0);
      A.j[1] = mkjob(mo, nullptr, 1024, 1024, rm_w, 1024, rm_b, nullptr,
                     mem_p, 1024, 0, 0, 0, 0);
      gemm_v4<<<dim3(64, 1, 2), 256, 0, stream>>>(A);
    }
    ctrl_att_kernel<<<32, 1024, 0, stream>>>(cq, context, ca_w, control);
    {  // G3: h = control @ riwsT.T   (N=2048, C=1024)
      GJobs A;
      A.j[0] = mkjob(control, nullptr, 1024, 1024, riwsT, 1024, nullptr, nullptr,
                     h, 2048, 0, 0, 0, 0);
      A.j[1] = A.j[0];
      gemm_v4<<<dim3(128, 1, 1), 256, 0, stream>>>(A);
    }
    ratt_kernel<<<dim3(32, 16), 512, 0, stream>>>(knowledge, mem_p, h, partial);
    read_kernel<<<dim3(32, 32), 256, 0, stream>>>(partial, knowledge, readv);
    {  // G6: new_memory = [read, memory] @ wm_w.T + wm_b
      GJobs A;
      A.j[0] = mkjob(readv, mo, 1024, 2048, wm_w, 2048, wm_b, nullptr,
                     mn, 1024, 0, 0, 0, 0);
      A.j[1] = A.j[0];
      gemm_v4<<<dim3(64, 1, 1), 256, 0, stream>>>(A);
    }
  }
}